// Round 1
// baseline (176.174 us; speedup 1.0000x reference)
//
#include <hip/hip_runtime.h>

// ---------------------------------------------------------------------------
// DeltaModel: B=256, L=2048, H=V=64.
//  (1) hs/k/v/q depend only on token id (V=64) -> 64-entry tables.
//  (2) r = M_N q -> backward scan with y_a = k_a . u for all 64 keys.
//  (3) NEW: 3-term lookahead (banded WY form) removes the cross-lane round
//      trip from the critical path:
//        s_j = p_j + cf1*s_{j-1} + cf2*s_{j-2} + cf3*s_{j-3}
//      with cf_w = -G(c_j, c_{j-w}) precomputed per step (packed float4 in
//      LDS, one uniform ds_read_b128/step), p_j = readlane(y, c_j) issued
//      one step early against a lag-2 y update. Chain = fma->add (~8 cy)
//      instead of fma->readlane->fma (~47 cy measured).
// ---------------------------------------------------------------------------

#define DPP_ADD_F32(x, ctrl, rm, bm, bc)                                      \
  (x) = (x) + __int_as_float(__builtin_amdgcn_update_dpp(                     \
            0, __float_as_int(x), (ctrl), (rm), (bm), (bc)))

__device__ __forceinline__ float wave_sum64(float x) {
  DPP_ADD_F32(x, 0x111, 0xf, 0xf, true);   // row_shr:1
  DPP_ADD_F32(x, 0x112, 0xf, 0xf, true);   // row_shr:2
  DPP_ADD_F32(x, 0x114, 0xf, 0xf, true);   // row_shr:4
  DPP_ADD_F32(x, 0x118, 0xf, 0xf, true);   // row_shr:8
  DPP_ADD_F32(x, 0x142, 0xa, 0xf, false);  // row_bcast:15
  DPP_ADD_F32(x, 0x143, 0xc, 0xf, false);  // row_bcast:31 -> lane 63 total
  return __int_as_float(__builtin_amdgcn_readlane(__float_as_int(x), 63));
}

__device__ __forceinline__ float readlane_f(float x, int lane) {
  return __int_as_float(__builtin_amdgcn_readlane(__float_as_int(x), lane));
}

// ---------------------------------------------------------------------------
// Kernel A: per-token tables k_n, v, q (weights staged in padded LDS).
// ---------------------------------------------------------------------------
__global__ __launch_bounds__(64) void build_tables(
    const float* __restrict__ embed, const float* __restrict__ W1,
    const float* __restrict__ b1, const float* __restrict__ W2,
    const float* __restrict__ b2, const float* __restrict__ gamma,
    const float* __restrict__ beta, const float* __restrict__ Wk,
    const float* __restrict__ Wv, const float* __restrict__ Wq,
    float* __restrict__ k_tab, float* __restrict__ v_tab,
    float* __restrict__ q_tab) {
  __shared__ float Wbuf[8448];
  __shared__ float e_s[64];
  __shared__ float f1_s[128];
  __shared__ float hs_s[64];
  const int tok = blockIdx.x;
  const int l = threadIdx.x;

  const float e = embed[tok * 64 + l];
  e_s[l] = e;
  for (int i = 0; i < 128; ++i) Wbuf[i * 65 + l] = W1[i * 64 + l];
  __syncthreads();

  float a0 = b1[l], a1 = b1[l + 64];
#pragma unroll
  for (int h = 0; h < 64; ++h) {
    a0 = fmaf(e_s[h], Wbuf[l * 65 + h], a0);
    a1 = fmaf(e_s[h], Wbuf[(l + 64) * 65 + h], a1);
  }
  f1_s[l] = fmaxf(a0, 0.f);
  f1_s[l + 64] = fmaxf(a1, 0.f);
  __syncthreads();

  for (int i = 0; i < 128; ++i)
    Wbuf[(i >> 1) * 131 + (i & 1) * 64 + l] = W2[i * 64 + l];
  __syncthreads();

  float acc = b2[l];
#pragma unroll
  for (int j = 0; j < 128; ++j) acc = fmaf(f1_s[j], Wbuf[l * 131 + j], acc);
  const float hval = e + acc;

  const float mu = wave_sum64(hval) * (1.f / 64.f);
  const float d = hval - mu;
  const float var = wave_sum64(d * d) * (1.f / 64.f);
  const float hs = d * (1.f / sqrtf(var + 1e-5f)) * gamma[l] + beta[l];
  hs_s[l] = hs;
  __syncthreads();

  for (int i = 0; i < 64; ++i) {
    Wbuf[i * 65 + l] = Wk[i * 64 + l];
    Wbuf[4224 + i * 65 + l] = Wv[i * 64 + l];
  }
  __syncthreads();
  float kk = 0.f, vv = 0.f;
#pragma unroll
  for (int h = 0; h < 64; ++h) {
    kk = fmaf(hs_s[h], Wbuf[l * 65 + h], kk);
    vv = fmaf(hs_s[h], Wbuf[4224 + l * 65 + h], vv);
  }
  __syncthreads();
  for (int i = 0; i < 64; ++i) Wbuf[i * 65 + l] = Wq[i * 64 + l];
  __syncthreads();
  float qq = 0.f;
#pragma unroll
  for (int h = 0; h < 64; ++h) qq = fmaf(hs_s[h], Wbuf[l * 65 + h], qq);

  float nrm = fmaxf(sqrtf(wave_sum64(kk * kk)), 1e-12f);
  k_tab[tok * 64 + l] = kk / nrm;
  v_tab[tok * 64 + l] = vv;
  q_tab[tok * 64 + l] = qq;
}

// ---------------------------------------------------------------------------
// Kernel B: GV[a][l] = {-G[a][l], v[a][l]} packed float2 (G NEGATED so every
// downstream correction/update is a positive fma); KQ[a][l] = q_a.k_l.
// ---------------------------------------------------------------------------
__global__ __launch_bounds__(64) void build_gram(
    const float* __restrict__ k_tab, const float* __restrict__ q_tab,
    const float* __restrict__ v_tab, float2* __restrict__ GV,
    float* __restrict__ KQ) {
  __shared__ float k_s[4160];
  __shared__ float q_s[64];
  const int a = blockIdx.x;
  const int l = threadIdx.x;
  for (int i = 0; i < 64; ++i) k_s[i * 65 + l] = k_tab[i * 64 + l];
  q_s[l] = q_tab[a * 64 + l];
  __syncthreads();
  float g = 0.f, kq = 0.f;
#pragma unroll
  for (int h = 0; h < 64; ++h) {
    g = fmaf(k_s[a * 65 + h], k_s[l * 65 + h], g);
    kq = fmaf(q_s[h], k_s[l * 65 + h], kq);
  }
  GV[a * 64 + l] = make_float2(-g, v_tab[a * 64 + l]);
  KQ[a * 64 + l] = kq;
}

// ---------------------------------------------------------------------------
// Kernel C: per-batch scan + head. One wave per batch. Lane a owns y_a.
// Lookahead-3 scalar recurrence; coefficients precomputed (vectorized) into
// cpk[j] = {cf1, cf2, cf3, tok*64}. Main loop per step:
//   - uniform ds_read_b128 of cpk[j+12]      (prefetch)
//   - readfirstlane token j+5 -> SGPR ring   (for col addr + p lane)
//   - ds_read_b64 of GV column j+5           (prefetch, used at j+7)
//   - readlane p_{j+1} from y (state y^{(j-2)}, 1-step slack both sides)
//   - s_j = fma(cf1, s_{j-1}, P_j) + p_j     (chain: fma->add, ~8 cy)
//   - seed/accumulate partials P_{j+3}, P_{j+2}
//   - y += s_{j-2} * (-G col);  r += s_{j-2} * v col   (lag-2 update)
// Slot 0 (t=2047, the q position) is a dummy: its token is forced to 64
// (zero row) in the coef pass, so its column and all couplings are 0.
// ---------------------------------------------------------------------------
__global__ __launch_bounds__(64, 1) void scan_head(
    const int* __restrict__ seq, const float2* __restrict__ GVg,
    const float* __restrict__ KQ, const float* __restrict__ Wrp,
    const float* __restrict__ brp, const float* __restrict__ Wout,
    const float* __restrict__ bout, float* __restrict__ out) {
  __shared__ float2 GV_s[4160];  // 65 rows of 64 (row 64 = zeros, dummy tok)
  __shared__ float4 cpk[2064];   // per-step packed coefs + token*64 (16 pads)
  __shared__ float tmp[64];
  const int b = blockIdx.x;
  const int l = threadIdx.x;

#pragma unroll
  for (int i = 0; i < 32; ++i)
    ((float4*)GV_s)[l + 64 * i] = ((const float4*)GVg)[l + 64 * i];
  GV_s[4096 + l] = make_float2(0.f, 0.f);
  if (l < 16) cpk[2048 + l] = make_float4(0.f, 0.f, 0.f, __int_as_float(4096));

  const int* tokp = seq + b * 2048;

  // ---- coefficient pre-pass: 32 wave-wide iterations -------------------
  for (int blk = 0; blk < 32; ++blk) {
    const int j = blk * 64 + l;  // step index; slot j <-> t = 2047 - j
    int t0 = 64, t1 = 64, t2 = 64, t3 = 64;
    if (j >= 1) t0 = tokp[2047 - j];  // this step's token
    if (j >= 2) t1 = tokp[2048 - j];  // token of step j-1
    if (j >= 3) t2 = tokp[2049 - j];  // token of step j-2
    if (j >= 4) t3 = tokp[2050 - j];  // token of step j-3
    float c1 = 0.f, c2 = 0.f, c3 = 0.f;
    if (t0 < 64) {                       // j==0: dummy slot, all coefs 0
      c1 = GV_s[t1 * 64 + t0].x;         // -G(c_j, c_{j-1}); row 64 -> 0
      c2 = GV_s[t2 * 64 + t0].x;
      c3 = GV_s[t3 * 64 + t0].x;
    }
    cpk[j] = make_float4(c1, c2, c3, __int_as_float(t0 * 64));
  }

  // ---- init y and rings ------------------------------------------------
  const int qt = tokp[2047];  // t=2047 token -> q
  float y = KQ[qt * 64 + l];  // y_a = k_a . q
  float r = 0.f;

  float4 K[16];   // cpk ring (read at +12)
  float2 C[16];   // GV column ring (issued +5, used at -2)
  float S[16];    // s ring
  float P[16];    // partial (w=2,3 corrections) ring
  int tks[16];    // SGPR token ring (tok*64)
#pragma unroll
  for (int i = 0; i < 16; ++i) {
    S[i] = 0.f;
    P[i] = 0.f;
    C[i] = make_float2(0.f, 0.f);
    tks[i] = 4096;
  }
#pragma unroll
  for (int i = 0; i < 12; ++i) K[i] = cpk[i];
#pragma unroll
  for (int i = 0; i < 5; ++i)
    tks[i] = __builtin_amdgcn_readfirstlane(__float_as_int(K[i].w));
#pragma unroll
  for (int i = 0; i < 5; ++i) C[i] = GV_s[tks[i] + l];
  float pP = readlane_f(y, (tks[0] >> 6) & 63);  // p_0 (dummy, harmless)

  // ---- main scan: 2048 steps, unrolled x16 so ring idx are static ------
  for (int n = 0; n < 2048; n += 16) {
#pragma unroll
    for (int u = 0; u < 16; ++u) {
      const int j = n + u;
      const int m = j & 15;
      // prefetch packed coefs for step j+12 (uniform b128)
      K[(j + 12) & 15] = cpk[j + 12];
      // extract token j+5 into SGPR ring; issue its column read
      tks[(j + 5) & 15] =
          __builtin_amdgcn_readfirstlane(__float_as_int(K[(j + 5) & 15].w));
      // p for step j+1: reads y^{(j-2)} (before this step's y update)
      const float p1 = readlane_f(y, (tks[(j + 1) & 15] >> 6) & 63);
      C[(j + 5) & 15] = GV_s[tks[(j + 5) & 15] + l];
      // s_j = p_j + cf1*s_{j-1} + (cf2*s_{j-2} + cf3*s_{j-3})
      const float sj = fmaf(K[m].x, S[(j - 1) & 15], P[m]) + pP;
      S[m] = sj;
      pP = p1;
      // seed / accumulate partials for steps j+3, j+2
      P[(j + 3) & 15] = K[(j + 3) & 15].z * sj;
      P[(j + 2) & 15] = fmaf(K[(j + 2) & 15].y, sj, P[(j + 2) & 15]);
      // lag-2 y/r update (columns hold {-G, v})
      const float s2 = S[(j - 2) & 15];
      y = fmaf(s2, C[(j - 2) & 15].x, y);
      r = fmaf(s2, C[(j - 2) & 15].y, r);
    }
  }
  // epilogue: pending r contributions for steps 2046, 2047 (y not needed)
  r = fmaf(S[2046 & 15], C[2046 & 15].y, r);
  r = fmaf(S[2047 & 15], C[2047 & 15].y, r);

  // ---- Head: r -> Wrp -> Wout (weights staged padded into GV_s memory) --
  float* Wb = (float*)GV_s;
  tmp[l] = r;
  for (int i = 0; i < 64; ++i) {
    Wb[i * 65 + l] = Wrp[i * 64 + l];
    Wb[4160 + i * 65 + l] = Wout[i * 64 + l];
  }
  __syncthreads();
  float acc = brp[l];
#pragma unroll
  for (int j = 0; j < 64; ++j) acc = fmaf(tmp[j], Wb[l * 65 + j], acc);
  __syncthreads();
  tmp[l] = acc;
  __syncthreads();
  float o = bout[l];
#pragma unroll
  for (int i = 0; i < 64; ++i) o = fmaf(tmp[i], Wb[4160 + l * 65 + i], o);
  out[b * 64 + l] = o;
}

extern "C" void kernel_launch(void* const* d_in, const int* in_sizes, int n_in,
                              void* d_out, int out_size, void* d_ws,
                              size_t ws_size, hipStream_t stream) {
  const int* seq = (const int*)d_in[0];
  const float* embed = (const float*)d_in[1];
  const float* W1 = (const float*)d_in[2];
  const float* b1 = (const float*)d_in[3];
  const float* W2 = (const float*)d_in[4];
  const float* b2 = (const float*)d_in[5];
  const float* gamma = (const float*)d_in[6];
  const float* beta = (const float*)d_in[7];
  const float* Wk = (const float*)d_in[8];
  const float* Wv = (const float*)d_in[9];
  const float* Wq = (const float*)d_in[10];
  const float* Wrp = (const float*)d_in[11];
  const float* brp = (const float*)d_in[12];
  const float* Wout = (const float*)d_in[13];
  const float* bout = (const float*)d_in[14];

  float* wsf = (float*)d_ws;
  float* k_tab = wsf;                   // 4096
  float* v_tab = wsf + 4096;            // 4096
  float* q_tab = wsf + 8192;            // 4096
  float2* GV = (float2*)(wsf + 12288);  // 4096 float2 = 8192 floats
  float* KQ = wsf + 20480;              // 4096

  build_tables<<<64, 64, 0, stream>>>(embed, W1, b1, W2, b2, gamma, beta, Wk,
                                      Wv, Wq, k_tab, v_tab, q_tab);
  build_gram<<<64, 64, 0, stream>>>(k_tab, q_tab, v_tab, GV, KQ);
  scan_head<<<256, 64, 0, stream>>>(seq, GV, KQ, Wrp, brp, Wout, bout,
                                    (float*)d_out);
}

// Round 3
// 149.059 us; speedup vs baseline: 1.1819x; 1.1819x over previous
//
#include <hip/hip_runtime.h>

// ---------------------------------------------------------------------------
// DeltaModel: B=256, L=2048, H=V=64.
//  (1) hs/k/v/q depend only on token id (V=64) -> 64-entry tables.
//  (2) r = M_N q -> backward scan = unit-lower-triangular solve:
//        s_j = y0[c_j] - sum_{i<j} G(c_j,c_i) s_i;  r = sum_j s_j v[c_j]
//  (3) Hierarchical block solve (64-step blocks):
//        - block start: cur_j = y[c_j] via ONE ds_bpermute (y carries all
//          cross-block history: y -= s_i G[:,c_i] per step, off-chain)
//        - in-block: s_i = v_readlane(cur, i)  [STATIC lane -> no SGPR-
//          select hazard], cur = fmaf(s_i, -G(c_j,c_i), cur)
//        - Gram coefs gathered from padded [65][65] -G table, prefetched
//          8 steps ahead (ring, static indices); GV columns likewise.
//      Chain = fma -> readlane(const) -> fma (~12cy) vs old ~47cy/step.
//      Operand order of every fma matches the old kernel (G symmetric,
//      fma multiplicands commute) -> bit-identical output.
// ---------------------------------------------------------------------------

#define DPP_ADD_F32(x, ctrl, rm, bm, bc)                                      \
  (x) = (x) + __int_as_float(__builtin_amdgcn_update_dpp(                     \
            0, __float_as_int(x), (ctrl), (rm), (bm), (bc)))

__device__ __forceinline__ float wave_sum64(float x) {
  DPP_ADD_F32(x, 0x111, 0xf, 0xf, true);   // row_shr:1
  DPP_ADD_F32(x, 0x112, 0xf, 0xf, true);   // row_shr:2
  DPP_ADD_F32(x, 0x114, 0xf, 0xf, true);   // row_shr:4
  DPP_ADD_F32(x, 0x118, 0xf, 0xf, true);   // row_shr:8
  DPP_ADD_F32(x, 0x142, 0xa, 0xf, false);  // row_bcast:15
  DPP_ADD_F32(x, 0x143, 0xc, 0xf, false);  // row_bcast:31 -> lane 63 total
  return __int_as_float(__builtin_amdgcn_readlane(__float_as_int(x), 63));
}

__device__ __forceinline__ float readlane_f(float x, int lane) {
  return __int_as_float(__builtin_amdgcn_readlane(__float_as_int(x), lane));
}

// ---------------------------------------------------------------------------
// Kernel A: per-token tables k_n, v, q (weights staged in padded LDS).
// ---------------------------------------------------------------------------
__global__ __launch_bounds__(64) void build_tables(
    const float* __restrict__ embed, const float* __restrict__ W1,
    const float* __restrict__ b1, const float* __restrict__ W2,
    const float* __restrict__ b2, const float* __restrict__ gamma,
    const float* __restrict__ beta, const float* __restrict__ Wk,
    const float* __restrict__ Wv, const float* __restrict__ Wq,
    float* __restrict__ k_tab, float* __restrict__ v_tab,
    float* __restrict__ q_tab) {
  __shared__ float Wbuf[8448];
  __shared__ float e_s[64];
  __shared__ float f1_s[128];
  __shared__ float hs_s[64];
  const int tok = blockIdx.x;
  const int l = threadIdx.x;

  const float e = embed[tok * 64 + l];
  e_s[l] = e;
  for (int i = 0; i < 128; ++i) Wbuf[i * 65 + l] = W1[i * 64 + l];
  __syncthreads();

  float a0 = b1[l], a1 = b1[l + 64];
#pragma unroll
  for (int h = 0; h < 64; ++h) {
    a0 = fmaf(e_s[h], Wbuf[l * 65 + h], a0);
    a1 = fmaf(e_s[h], Wbuf[(l + 64) * 65 + h], a1);
  }
  f1_s[l] = fmaxf(a0, 0.f);
  f1_s[l + 64] = fmaxf(a1, 0.f);
  __syncthreads();

  for (int i = 0; i < 128; ++i)
    Wbuf[(i >> 1) * 131 + (i & 1) * 64 + l] = W2[i * 64 + l];
  __syncthreads();

  float acc = b2[l];
#pragma unroll
  for (int j = 0; j < 128; ++j) acc = fmaf(f1_s[j], Wbuf[l * 131 + j], acc);
  const float hval = e + acc;

  const float mu = wave_sum64(hval) * (1.f / 64.f);
  const float d = hval - mu;
  const float var = wave_sum64(d * d) * (1.f / 64.f);
  const float hs = d * (1.f / sqrtf(var + 1e-5f)) * gamma[l] + beta[l];
  hs_s[l] = hs;
  __syncthreads();

  for (int i = 0; i < 64; ++i) {
    Wbuf[i * 65 + l] = Wk[i * 64 + l];
    Wbuf[4224 + i * 65 + l] = Wv[i * 64 + l];
  }
  __syncthreads();
  float kk = 0.f, vv = 0.f;
#pragma unroll
  for (int h = 0; h < 64; ++h) {
    kk = fmaf(hs_s[h], Wbuf[l * 65 + h], kk);
    vv = fmaf(hs_s[h], Wbuf[4224 + l * 65 + h], vv);
  }
  __syncthreads();
  for (int i = 0; i < 64; ++i) Wbuf[i * 65 + l] = Wq[i * 64 + l];
  __syncthreads();
  float qq = 0.f;
#pragma unroll
  for (int h = 0; h < 64; ++h) qq = fmaf(hs_s[h], Wbuf[l * 65 + h], qq);

  float nrm = fmaxf(sqrtf(wave_sum64(kk * kk)), 1e-12f);
  k_tab[tok * 64 + l] = kk / nrm;
  v_tab[tok * 64 + l] = vv;
  q_tab[tok * 64 + l] = qq;
}

// ---------------------------------------------------------------------------
// Kernel B: GV[a][l] = {-G[a][l], v[a][l]} packed float2 (G NEGATED so every
// downstream correction/update is a positive fma); KQ[a][l] = q_a.k_l.
// ---------------------------------------------------------------------------
__global__ __launch_bounds__(64) void build_gram(
    const float* __restrict__ k_tab, const float* __restrict__ q_tab,
    const float* __restrict__ v_tab, float2* __restrict__ GV,
    float* __restrict__ KQ) {
  __shared__ float k_s[4160];
  __shared__ float q_s[64];
  const int a = blockIdx.x;
  const int l = threadIdx.x;
  for (int i = 0; i < 64; ++i) k_s[i * 65 + l] = k_tab[i * 64 + l];
  q_s[l] = q_tab[a * 64 + l];
  __syncthreads();
  float g = 0.f, kq = 0.f;
#pragma unroll
  for (int h = 0; h < 64; ++h) {
    g = fmaf(k_s[a * 65 + h], k_s[l * 65 + h], g);
    kq = fmaf(q_s[h], k_s[l * 65 + h], kq);
  }
  GV[a * 64 + l] = make_float2(-g, v_tab[a * 64 + l]);
  KQ[a * 64 + l] = kq;
}

// ---------------------------------------------------------------------------
// Kernel C: per-batch scan + head. One wave per batch.
// ---------------------------------------------------------------------------
__global__ __launch_bounds__(64, 1) void scan_head(
    const int* __restrict__ seq, const float2* __restrict__ GVg,
    const float* __restrict__ KQ, const float* __restrict__ Wrp,
    const float* __restrict__ brp, const float* __restrict__ Wout,
    const float* __restrict__ bout, float* __restrict__ out) {
  __shared__ float2 GV_s[4160];  // 65 rows of 64 (row 64 = zeros, dummy tok)
  __shared__ float G32_s[4225];  // padded [65][65]: -G, row 64 & col 64 zero
  __shared__ float tmp[64];
  const int b = blockIdx.x;
  const int l = threadIdx.x;

#pragma unroll
  for (int i = 0; i < 32; ++i)
    ((float4*)GV_s)[l + 64 * i] = ((const float4*)GVg)[l + 64 * i];
  GV_s[4096 + l] = make_float2(0.f, 0.f);

  // padded float copy of -G: G32_s[a*65+t] = -G(a,t); zero row/col 64.
#pragma unroll 8
  for (int i = 0; i < 64; ++i) G32_s[i * 65 + l] = GV_s[i * 64 + l].x;
  G32_s[64 * 65 + l] = 0.f;
  G32_s[l * 65 + 64] = 0.f;
  if (l == 0) G32_s[64 * 65 + 64] = 0.f;
  __syncthreads();

  const int* tokp = seq + b * 2048;
  const int qt = tokp[2047];   // t=2047 token -> q
  float y = KQ[qt * 64 + l];   // y_a = k_a . q
  float r = 0.f;

  // block tokens: slot j of block nb <-> t = 2047 - (64*nb + j)
  int tokA = tokp[2047 - l];   // block 0
  if (l == 0) tokA = 64;       // global step 0 = dummy (zero row/col)
  int rowA = tokA * 65;        // per-lane row base in G32_s
  int tokB = tokp[2047 - 64 - l];  // block 1
  int rowB = tokB * 65;

  // prefetch rings (distance 8, static indices)
  float g_pre[8];
  float2 gv_pre[8];
#pragma unroll
  for (int i = 0; i < 8; ++i) {
    const int st = __builtin_amdgcn_readlane(tokA, i);
    g_pre[i] = G32_s[rowA + st];
    gv_pre[i] = GV_s[st * 64 + l];
  }

  // One 64-step block: tkC/rwC = this block's tokens/rows, tkN/rwN = next.
  auto body = [&](int tkC, int rwC, int tkN, int rwN) {
    // gather cur_j = y[c_j] (one bpermute; dummy tok 64 -> lane 0, harmless)
    float cur = __int_as_float(__builtin_amdgcn_ds_bpermute(
        (tkC & 63) << 2, __float_as_int(y)));
#pragma unroll
    for (int i = 0; i < 64; ++i) {
      const float gi = g_pre[i & 7];      // -G(c_j, c_i), prefetched
      const float2 gvi = gv_pre[i & 7];   // {-G[c_i][a], v[c_i][a]}
      const int ip = i + 8;               // prefetch for step i+8
      const int st = (ip < 64) ? __builtin_amdgcn_readlane(tkC, ip)
                               : __builtin_amdgcn_readlane(tkN, ip & 63);
      g_pre[i & 7] = G32_s[(ip < 64 ? rwC : rwN) + st];
      gv_pre[i & 7] = GV_s[st * 64 + l];
      // serial chain: static-lane readlane -> fma
      const float s = readlane_f(cur, i);
      cur = fmaf(s, gi, cur);
      // off-chain history carriers (bit-identical to per-step y update)
      y = fmaf(s, gvi.x, y);
      r = fmaf(s, gvi.y, r);
    }
  };

  for (int n = 0; n < 16; ++n) {
    int tokC = (n < 15) ? tokp[2047 - 64 * (2 * n + 2) - l] : 64;
    body(tokA, rowA, tokB, rowB);  // block 2n
    const int rowC = tokC * 65;
    int tokD = (n < 15) ? tokp[2047 - 64 * (2 * n + 3) - l] : 64;
    body(tokB, rowB, tokC, rowC);  // block 2n+1
    const int rowD = tokD * 65;
    tokA = tokC;
    rowA = rowC;
    tokB = tokD;
    rowB = rowD;
  }

  // ---- Head: r -> Wrp -> Wout (weights staged padded into GV_s memory) --
  float* Wb = (float*)GV_s;
  tmp[l] = r;
  for (int i = 0; i < 64; ++i) {
    Wb[i * 65 + l] = Wrp[i * 64 + l];
    Wb[4160 + i * 65 + l] = Wout[i * 64 + l];
  }
  __syncthreads();
  float acc = brp[l];
#pragma unroll
  for (int j = 0; j < 64; ++j) acc = fmaf(tmp[j], Wb[l * 65 + j], acc);
  __syncthreads();
  tmp[l] = acc;
  __syncthreads();
  float o = bout[l];
#pragma unroll
  for (int i = 0; i < 64; ++i) o = fmaf(tmp[i], Wb[4160 + l * 65 + i], o);
  out[b * 64 + l] = o;
}

extern "C" void kernel_launch(void* const* d_in, const int* in_sizes, int n_in,
                              void* d_out, int out_size, void* d_ws,
                              size_t ws_size, hipStream_t stream) {
  const int* seq = (const int*)d_in[0];
  const float* embed = (const float*)d_in[1];
  const float* W1 = (const float*)d_in[2];
  const float* b1 = (const float*)d_in[3];
  const float* W2 = (const float*)d_in[4];
  const float* b2 = (const float*)d_in[5];
  const float* gamma = (const float*)d_in[6];
  const float* beta = (const float*)d_in[7];
  const float* Wk = (const float*)d_in[8];
  const float* Wv = (const float*)d_in[9];
  const float* Wq = (const float*)d_in[10];
  const float* Wrp = (const float*)d_in[11];
  const float* brp = (const float*)d_in[12];
  const float* Wout = (const float*)d_in[13];
  const float* bout = (const float*)d_in[14];

  float* wsf = (float*)d_ws;
  float* k_tab = wsf;                   // 4096
  float* v_tab = wsf + 4096;            // 4096
  float* q_tab = wsf + 8192;            // 4096
  float2* GV = (float2*)(wsf + 12288);  // 4096 float2 = 8192 floats
  float* KQ = wsf + 20480;              // 4096

  build_tables<<<64, 64, 0, stream>>>(embed, W1, b1, W2, b2, gamma, beta, Wk,
                                      Wv, Wq, k_tab, v_tab, q_tab);
  build_gram<<<64, 64, 0, stream>>>(k_tab, q_tab, v_tab, GV, KQ);
  scan_head<<<256, 64, 0, stream>>>(seq, GV, KQ, Wrp, brp, Wout, bout,
                                    (float*)d_out);
}

// Round 4
// 148.728 us; speedup vs baseline: 1.1845x; 1.0022x over previous
//
#include <hip/hip_runtime.h>

// ---------------------------------------------------------------------------
// DeltaModel: B=256, L=2048, H=V=64.
//  (1) hs/k/v/q depend only on token id (V=64) -> 64-entry tables.
//  (2) r = M_N q -> backward scan: s_j = y^{(j-1)}[c_j], y -= s_j G[:,c_j],
//      r += s_j v[c_j].
//  (3) Lookahead-1 scalar recurrence, ZERO extra tables:
//        s_j = fmaf(cf_j, s_{j-1}, p_j)
//        p_j  = readlane(y^{(j-2)}, c_j)      (lane select = SGPR, written a
//                                              batch earlier -> no hazard)
//        cf_j = readlane(col_{j-1}.x, c_j)    (= -G(c_j,c_{j-1}), from the
//                                              column ALREADY loaded)
//      This is algebraically AND bit-wise identical to reading y after the
//      j-1 update (same single fma), but the cross-lane round trip is spread
//      over 2 steps instead of sitting whole on the chain.
//      Columns are loaded in batches of 8 ds_read_b64 into double-buffered
//      NAMED registers (straight-line code -> compiler emits counted
//      lgkmcnt, no per-step drains).
// ---------------------------------------------------------------------------

#define DPP_ADD_F32(x, ctrl, rm, bm, bc)                                      \
  (x) = (x) + __int_as_float(__builtin_amdgcn_update_dpp(                     \
            0, __float_as_int(x), (ctrl), (rm), (bm), (bc)))

__device__ __forceinline__ float wave_sum64(float x) {
  DPP_ADD_F32(x, 0x111, 0xf, 0xf, true);   // row_shr:1
  DPP_ADD_F32(x, 0x112, 0xf, 0xf, true);   // row_shr:2
  DPP_ADD_F32(x, 0x114, 0xf, 0xf, true);   // row_shr:4
  DPP_ADD_F32(x, 0x118, 0xf, 0xf, true);   // row_shr:8
  DPP_ADD_F32(x, 0x142, 0xa, 0xf, false);  // row_bcast:15
  DPP_ADD_F32(x, 0x143, 0xc, 0xf, false);  // row_bcast:31 -> lane 63 total
  return __int_as_float(__builtin_amdgcn_readlane(__float_as_int(x), 63));
}

__device__ __forceinline__ float readlane_f(float x, int lane) {
  return __int_as_float(__builtin_amdgcn_readlane(__float_as_int(x), lane));
}

// ---------------------------------------------------------------------------
// Kernel A: per-token tables k_n, v, q (weights staged in padded LDS).
// ---------------------------------------------------------------------------
__global__ __launch_bounds__(64) void build_tables(
    const float* __restrict__ embed, const float* __restrict__ W1,
    const float* __restrict__ b1, const float* __restrict__ W2,
    const float* __restrict__ b2, const float* __restrict__ gamma,
    const float* __restrict__ beta, const float* __restrict__ Wk,
    const float* __restrict__ Wv, const float* __restrict__ Wq,
    float* __restrict__ k_tab, float* __restrict__ v_tab,
    float* __restrict__ q_tab) {
  __shared__ float Wbuf[8448];
  __shared__ float e_s[64];
  __shared__ float f1_s[128];
  __shared__ float hs_s[64];
  const int tok = blockIdx.x;
  const int l = threadIdx.x;

  const float e = embed[tok * 64 + l];
  e_s[l] = e;
  for (int i = 0; i < 128; ++i) Wbuf[i * 65 + l] = W1[i * 64 + l];
  __syncthreads();

  float a0 = b1[l], a1 = b1[l + 64];
#pragma unroll
  for (int h = 0; h < 64; ++h) {
    a0 = fmaf(e_s[h], Wbuf[l * 65 + h], a0);
    a1 = fmaf(e_s[h], Wbuf[(l + 64) * 65 + h], a1);
  }
  f1_s[l] = fmaxf(a0, 0.f);
  f1_s[l + 64] = fmaxf(a1, 0.f);
  __syncthreads();

  for (int i = 0; i < 128; ++i)
    Wbuf[(i >> 1) * 131 + (i & 1) * 64 + l] = W2[i * 64 + l];
  __syncthreads();

  float acc = b2[l];
#pragma unroll
  for (int j = 0; j < 128; ++j) acc = fmaf(f1_s[j], Wbuf[l * 131 + j], acc);
  const float hval = e + acc;

  const float mu = wave_sum64(hval) * (1.f / 64.f);
  const float d = hval - mu;
  const float var = wave_sum64(d * d) * (1.f / 64.f);
  const float hs = d * (1.f / sqrtf(var + 1e-5f)) * gamma[l] + beta[l];
  hs_s[l] = hs;
  __syncthreads();

  for (int i = 0; i < 64; ++i) {
    Wbuf[i * 65 + l] = Wk[i * 64 + l];
    Wbuf[4224 + i * 65 + l] = Wv[i * 64 + l];
  }
  __syncthreads();
  float kk = 0.f, vv = 0.f;
#pragma unroll
  for (int h = 0; h < 64; ++h) {
    kk = fmaf(hs_s[h], Wbuf[l * 65 + h], kk);
    vv = fmaf(hs_s[h], Wbuf[4224 + l * 65 + h], vv);
  }
  __syncthreads();
  for (int i = 0; i < 64; ++i) Wbuf[i * 65 + l] = Wq[i * 64 + l];
  __syncthreads();
  float qq = 0.f;
#pragma unroll
  for (int h = 0; h < 64; ++h) qq = fmaf(hs_s[h], Wbuf[l * 65 + h], qq);

  float nrm = fmaxf(sqrtf(wave_sum64(kk * kk)), 1e-12f);
  k_tab[tok * 64 + l] = kk / nrm;
  v_tab[tok * 64 + l] = vv;
  q_tab[tok * 64 + l] = qq;
}

// ---------------------------------------------------------------------------
// Kernel B: GV[a][l] = {-G[a][l], v[a][l]} packed float2 (G NEGATED so every
// downstream update is a positive fma); KQ[a][l] = q_a.k_l.
// ---------------------------------------------------------------------------
__global__ __launch_bounds__(64) void build_gram(
    const float* __restrict__ k_tab, const float* __restrict__ q_tab,
    const float* __restrict__ v_tab, float2* __restrict__ GV,
    float* __restrict__ KQ) {
  __shared__ float k_s[4160];
  __shared__ float q_s[64];
  const int a = blockIdx.x;
  const int l = threadIdx.x;
  for (int i = 0; i < 64; ++i) k_s[i * 65 + l] = k_tab[i * 64 + l];
  q_s[l] = q_tab[a * 64 + l];
  __syncthreads();
  float g = 0.f, kq = 0.f;
#pragma unroll
  for (int h = 0; h < 64; ++h) {
    g = fmaf(k_s[a * 65 + h], k_s[l * 65 + h], g);
    kq = fmaf(q_s[h], k_s[l * 65 + h], kq);
  }
  GV[a * 64 + l] = make_float2(-g, v_tab[a * 64 + l]);
  KQ[a * 64 + l] = kq;
}

// ---------------------------------------------------------------------------
// Kernel C: per-batch scan + head. One wave per batch.
// ---------------------------------------------------------------------------
__global__ __launch_bounds__(64, 1) void scan_head(
    const int* __restrict__ seq, const float2* __restrict__ GVg,
    const float* __restrict__ KQ, const float* __restrict__ Wrp,
    const float* __restrict__ brp, const float* __restrict__ Wout,
    const float* __restrict__ bout, float* __restrict__ out) {
  __shared__ float2 GV_s[4160];  // 65 rows of 64 (row 64 = zeros, dummy tok)
  __shared__ float tmp[64];
  const int b = blockIdx.x;
  const int l = threadIdx.x;

#pragma unroll
  for (int i = 0; i < 32; ++i)
    ((float4*)GV_s)[l + 64 * i] = ((const float4*)GVg)[l + 64 * i];
  GV_s[4096 + l] = make_float2(0.f, 0.f);
  __syncthreads();

  const int* tokp = seq + b * 2048;
  const int qt = tokp[2047];  // t=2047 token -> q
  float y = KQ[qt * 64 + l];  // y_a = k_a . q
  float r = 0.f;

  // block tokens: slot j of block nb <-> t = 2047 - (64*nb + j)
  int tokA = (l == 0) ? 64 : tokp[2047 - l];  // block 0 (slot 0 = dummy)
  int tokB = tokp[2047 - 64 - l];             // block 1

  // double-buffered column registers + token-value registers (sel = 0..64)
  float2 colX[8], colY[8];
  int selX[8], selY[8];

  // prologue: batch 0 selects + column loads into X
#pragma unroll
  for (int k = 0; k < 8; ++k) {
    selX[k] = __builtin_amdgcn_readlane(tokA, k);
    colX[k] = GV_s[selX[k] * 64 + l];
  }
  float s_prev = 0.f;
  float cf_cur = 0.f;                        // step 0 has no lookahead term
  float p_cur = readlane_f(y, selX[0] & 63); // dummy tok 64 -> lane 0

  // one 8-step batch: consume (cC,sC); extract+load next batch into (cN,sN)
  auto BATCH = [&](float2 (&cC)[8], int (&sC)[8], float2 (&cN)[8],
                   int (&sN)[8], int tokvec, int lane_base) {
#pragma unroll
    for (int k = 0; k < 8; ++k) {
      sN[k] = __builtin_amdgcn_readlane(tokvec, lane_base + k);
      cN[k] = GV_s[sN[k] * 64 + l];
    }
#pragma unroll
    for (int k = 0; k < 8; ++k) {
      const int nsel = ((k < 7) ? sC[k + 1] : sN[0]) & 63;
      const float p_next = readlane_f(y, nsel);        // reads y^{(i-1)}
      const float s_i = fmaf(cf_cur, s_prev, p_cur);   // chain: pure VALU
      const float cf_next = readlane_f(cC[k].x, nsel); // -G(c_{i+1}, c_i)
      y = fmaf(s_i, cC[k].x, y);
      r = fmaf(s_i, cC[k].y, r);
      p_cur = p_next;
      cf_cur = cf_next;
      s_prev = s_i;
    }
  };

  for (int blk = 0; blk < 32; ++blk) {
    BATCH(colX, selX, colY, selY, tokA, 8);
    BATCH(colY, selY, colX, selX, tokA, 16);
    BATCH(colX, selX, colY, selY, tokA, 24);
    BATCH(colY, selY, colX, selX, tokA, 32);
    BATCH(colX, selX, colY, selY, tokA, 40);
    BATCH(colY, selY, colX, selX, tokA, 48);
    BATCH(colX, selX, colY, selY, tokA, 56);
    BATCH(colY, selY, colX, selX, tokB, 0);  // next block's batch 0
    tokA = tokB;
    tokB = (blk + 2 < 32) ? tokp[2047 - 64 * (blk + 2) - l] : 64;
  }

  // ---- Head: r -> Wrp -> Wout (weights staged padded into GV_s memory) --
  float* Wb = (float*)GV_s;
  tmp[l] = r;
  __syncthreads();
  for (int i = 0; i < 64; ++i) {
    Wb[i * 65 + l] = Wrp[i * 64 + l];
    Wb[4160 + i * 65 + l] = Wout[i * 64 + l];
  }
  __syncthreads();
  float acc = brp[l];
#pragma unroll
  for (int j = 0; j < 64; ++j) acc = fmaf(tmp[j], Wb[l * 65 + j], acc);
  __syncthreads();
  tmp[l] = acc;
  __syncthreads();
  float o = bout[l];
#pragma unroll
  for (int i = 0; i < 64; ++i) o = fmaf(tmp[i], Wb[4160 + l * 65 + i], o);
  out[b * 64 + l] = o;
}

extern "C" void kernel_launch(void* const* d_in, const int* in_sizes, int n_in,
                              void* d_out, int out_size, void* d_ws,
                              size_t ws_size, hipStream_t stream) {
  const int* seq = (const int*)d_in[0];
  const float* embed = (const float*)d_in[1];
  const float* W1 = (const float*)d_in[2];
  const float* b1 = (const float*)d_in[3];
  const float* W2 = (const float*)d_in[4];
  const float* b2 = (const float*)d_in[5];
  const float* gamma = (const float*)d_in[6];
  const float* beta = (const float*)d_in[7];
  const float* Wk = (const float*)d_in[8];
  const float* Wv = (const float*)d_in[9];
  const float* Wq = (const float*)d_in[10];
  const float* Wrp = (const float*)d_in[11];
  const float* brp = (const float*)d_in[12];
  const float* Wout = (const float*)d_in[13];
  const float* bout = (const float*)d_in[14];

  float* wsf = (float*)d_ws;
  float* k_tab = wsf;                   // 4096
  float* v_tab = wsf + 4096;            // 4096
  float* q_tab = wsf + 8192;            // 4096
  float2* GV = (float2*)(wsf + 12288);  // 4096 float2 = 8192 floats
  float* KQ = wsf + 20480;              // 4096

  build_tables<<<64, 64, 0, stream>>>(embed, W1, b1, W2, b2, gamma, beta, Wk,
                                      Wv, Wq, k_tab, v_tab, q_tab);
  build_gram<<<64, 64, 0, stream>>>(k_tab, q_tab, v_tab, GV, KQ);
  scan_head<<<256, 64, 0, stream>>>(seq, GV, KQ, Wrp, brp, Wout, bout,
                                    (float*)d_out);
}